// Round 11
// baseline (215.194 us; speedup 1.0000x reference)
//
#include <hip/hip_runtime.h>
#include <math.h>

#define SEQLEN    4096
#define DIM_IN    1024
#define D_INNER   2048
#define N_HEADS   32
#define D_STATE   128
#define CONV_DIM  2304      // D_INNER + 2*D_STATE
#define D_IN_PROJ 4384      // 2*D_INNER + 2*D_STATE + N_HEADS
#define PROJ_LD   4480      // padded to 35*128 so GEMM1 N-tiles need no guard
#define LN_EPS    1e-5f
#define KV_SPLIT  16        // L-chunks (256 l each) for the KV partial reduction

typedef __attribute__((ext_vector_type(8))) short bf16x8;
typedef __attribute__((ext_vector_type(4))) float f32x4;
typedef __attribute__((ext_vector_type(8))) short short8;

__device__ __forceinline__ ushort f2bf(float f) {
    union { float f; unsigned u; } v; v.f = f;
    unsigned u = v.u + 0x7FFFu + ((v.u >> 16) & 1u);   // RNE
    return (ushort)(u >> 16);
}
__device__ __forceinline__ float bf2f(ushort h) {
    union { unsigned u; float f; } v; v.u = ((unsigned)h) << 16;
    return v.f;
}

__device__ __forceinline__ void gload16(const void* g, void* l) {
    __builtin_amdgcn_global_load_lds(
        (const __attribute__((address_space(1))) void*)g,
        (__attribute__((address_space(3))) void*)l, 16, 0, 0);
}

// ---------------- fused fp32 -> bf16 converts (x, W_in padded, W_out) ----------------
#define XB_GROUPS   (SEQLEN * DIM_IN / 8)              // 65536
#define WIN_GROUPS  (PROJ_LD * DIM_IN / 8)             // 573440
#define WOUT_GROUPS (DIM_IN * D_INNER / 8)             // 262144
__global__ __launch_bounds__(256)
void cvt_all(const float* __restrict__ x, const float* __restrict__ W_in,
             const float* __restrict__ W_out,
             ushort* __restrict__ xb, ushort* __restrict__ Winb,
             ushort* __restrict__ Woutb) {
    int i = blockIdx.x * 256 + threadIdx.x;
    const float* src;
    ushort* dst;
    int gi;
    if (i < XB_GROUPS) {
        src = x; dst = xb; gi = i;
    } else if (i < XB_GROUPS + WIN_GROUPS) {
        gi = i - XB_GROUPS;
        int row = (gi * 8) >> 10;
        if (row >= D_IN_PROJ) {   // zero pad rows
            *reinterpret_cast<short8*>(&Winb[(size_t)gi * 8]) = (short8){0,0,0,0,0,0,0,0};
            return;
        }
        src = W_in; dst = Winb;
    } else if (i < XB_GROUPS + WIN_GROUPS + WOUT_GROUPS) {
        gi = i - (XB_GROUPS + WIN_GROUPS);
        src = W_out; dst = Woutb;
    } else return;
    float4 v0 = reinterpret_cast<const float4*>(src)[gi * 2];
    float4 v1 = reinterpret_cast<const float4*>(src)[gi * 2 + 1];
    short8 r;
    r[0] = f2bf(v0.x); r[1] = f2bf(v0.y); r[2] = f2bf(v0.z); r[3] = f2bf(v0.w);
    r[4] = f2bf(v1.x); r[5] = f2bf(v1.y); r[6] = f2bf(v1.z); r[7] = f2bf(v1.w);
    *reinterpret_cast<short8*>(&dst[(size_t)gi * 8]) = r;
}
#define CVT_TOTAL (XB_GROUPS + WIN_GROUPS + WOUT_GROUPS)

// ============ 8-phase pipelined bf16 NT GEMM (GEMM1): T3+T4 schedule ============
// BM=256, BN=128, BK=64, 512 threads (8 waves, 4M x 2N, per-wave 64x64).
// Per K-tile: 4 phases = 4 C-quadrants; each phase {8 ds_read_b128 | 1-2 staging
// issues for tile t+2 | barrier | lgkmcnt(0) | setprio(1) 8xMFMA setprio(0) |
// [p==3: vmcnt(6) counted, never 0 mid-loop] | barrier}. Ring-3 LDS 144 KB.
// Swizzle (rule 21, both sides): LDS(row,slot j) holds global slot j^(row&7);
// staged via pre-swizzled per-lane global src; ds_read applies same XOR.
template<int NT, int NTB>
__global__ __launch_bounds__(512, 2)
void gemm_bf16_big(const ushort* __restrict__ A, int lda,
                   const ushort* __restrict__ B, int ldb,
                   ushort* __restrict__ Cout, int ldc) {
    // per buffer: A 256 rows x 64k at [0..16383], B 128 rows x 64k at [16384..24575]
    __shared__ __align__(16) ushort S[3 * 24576];   // 144 KB

    const int nwg = gridDim.x;
    const int wg  = blockIdx.x;
    const int swz = (wg & 7) * (nwg >> 3) + (wg >> 3);   // bijective, nwg%8==0
    const int m0 = (swz / NTB) * 256;     // N-fastest: A-tile stays L2-resident
    const int n0 = (swz % NTB) * 128;

    const int tid  = threadIdx.x;
    const int wave = tid >> 6;           // 0..7
    const int lane = tid & 63;
    const int wr = wave >> 1;            // 0..3: rows wr*64
    const int wc = wave & 1;             // 0..1: cols wc*64
    const int r16 = lane & 15;
    const int kg  = lane >> 4;
    const int sx  = r16 & 7;             // ds_read slot XOR key (row&7 == r16&7)

    f32x4 acc[4][4];
    #pragma unroll
    for (int i = 0; i < 4; ++i)
        #pragma unroll
        for (int j = 0; j < 4; ++j) acc[i][j] = (f32x4){0.f, 0.f, 0.f, 0.f};

    // staging: 48 units of 8 rows x 64k (1 KB); wave w owns units 6w..6w+5.
    // unit u<32: A rows [8u,8u+8); else B rows [8(u-32),..). lane l -> row +=(l>>3),
    // slot l&7; global src slot = (l&7) ^ ((l>>3)&7)  (inverse swizzle).
    const int lr = lane >> 3;                      // 0..7 row-in-unit
    const int lslot = (lane & 7) ^ (lr & 7);       // pre-swizzled global slot
    const ushort* gsrc[6];
    int ldsoff[6];
    #pragma unroll
    for (int i = 0; i < 6; ++i) {
        int u = wave * 6 + i;
        if (u < 32) {
            gsrc[i] = A + (size_t)(m0 + 8 * u + lr) * lda + lslot * 8;
            ldsoff[i] = u * 512;
        } else {
            gsrc[i] = B + (size_t)(n0 + 8 * (u - 32) + lr) * ldb + lslot * 8;
            ldsoff[i] = 16384 + (u - 32) * 512;
        }
    }

#define ISSUE_UNIT(I, T, BUF) \
    gload16(gsrc[I] + (T) * 64, &S[(BUF) * 24576 + ldsoff[I]]);

    // prologue: tiles 0 -> buf0, 1 -> buf1 (12 issues/thread)
    #pragma unroll
    for (int i = 0; i < 6; ++i) { ISSUE_UNIT(i, 0, 0) }
    #pragma unroll
    for (int i = 0; i < 6; ++i) { ISSUE_UNIT(i, 1, 1) }
    asm volatile("s_waitcnt vmcnt(6)" ::: "memory");   // tile 0 landed; tile 1 in flight
    __builtin_amdgcn_s_barrier();

    for (int t = 0; t < NT; ++t) {
        const int rb = t % 3;
        const int sb = (t + 2) % 3;
        const ushort* bufA = &S[rb * 24576];
        const ushort* bufB = bufA + 16384;
        const bool pre = (t + 2 < NT);

        #pragma unroll
        for (int p = 0; p < 4; ++p) {
            const int pm = p >> 1, pn = p & 1;
            // ds_read this quadrant's fragments (4 a + 4 b)
            bf16x8 a[2][2], b[2][2];
            #pragma unroll
            for (int mi = 0; mi < 2; ++mi)
                #pragma unroll
                for (int s = 0; s < 2; ++s) {
                    int row = wr * 64 + pm * 32 + mi * 16 + r16;
                    int slot = (s * 4 + kg) ^ sx;
                    a[mi][s] = *reinterpret_cast<const bf16x8*>(&bufA[row * 64 + slot * 8]);
                }
            #pragma unroll
            for (int ni = 0; ni < 2; ++ni)
                #pragma unroll
                for (int s = 0; s < 2; ++s) {
                    int row = wc * 64 + pn * 32 + ni * 16 + r16;
                    int slot = (s * 4 + kg) ^ sx;
                    b[ni][s] = *reinterpret_cast<const bf16x8*>(&bufB[row * 64 + slot * 8]);
                }
            // staging issues for tile t+2 (2,2,1,1 across phases)
            if (pre) {
                if (p == 0)      { ISSUE_UNIT(0, t + 2, sb) ISSUE_UNIT(1, t + 2, sb) }
                else if (p == 1) { ISSUE_UNIT(2, t + 2, sb) ISSUE_UNIT(3, t + 2, sb) }
                else if (p == 2) { ISSUE_UNIT(4, t + 2, sb) }
                else             { ISSUE_UNIT(5, t + 2, sb) }
            }
            __builtin_amdgcn_s_barrier();
            asm volatile("s_waitcnt lgkmcnt(0)" ::: "memory");
            __builtin_amdgcn_sched_barrier(0);
            __builtin_amdgcn_s_setprio(1);
            #pragma unroll
            for (int mi = 0; mi < 2; ++mi)
                #pragma unroll
                for (int ni = 0; ni < 2; ++ni)
                    #pragma unroll
                    for (int s = 0; s < 2; ++s)
                        acc[pm * 2 + mi][pn * 2 + ni] =
                            __builtin_amdgcn_mfma_f32_16x16x32_bf16(
                                a[mi][s], b[ni][s], acc[pm * 2 + mi][pn * 2 + ni], 0, 0, 0);
            __builtin_amdgcn_s_setprio(0);
            if (p == 3) {   // tile boundary: next tile's buffer must be landed
                if (pre) asm volatile("s_waitcnt vmcnt(6)" ::: "memory");
                else     asm volatile("s_waitcnt vmcnt(0)" ::: "memory");
            }
            __builtin_amdgcn_s_barrier();
        }
    }
#undef ISSUE_UNIT

    // epilogue: acc -> LDS bf16 (256 x 136 padded) -> coalesced 16B stores
    ushort* EP = &S[0];
    __syncthreads();
    #pragma unroll
    for (int mi = 0; mi < 4; ++mi)
        #pragma unroll
        for (int ni = 0; ni < 4; ++ni)
            #pragma unroll
            for (int r = 0; r < 4; ++r)
                EP[(wr * 64 + mi * 16 + kg * 4 + r) * 136 + wc * 64 + ni * 16 + r16] =
                    f2bf(acc[mi][ni][r]);
    __syncthreads();
    #pragma unroll
    for (int i = 0; i < 8; ++i) {
        int idx = tid + 512 * i;           // 4096 chunks of 16B over 256x128
        int row = idx >> 4;
        int cb  = idx & 15;
        bf16x8 v = *reinterpret_cast<const bf16x8*>(&EP[row * 136 + cb * 8]);
        *reinterpret_cast<bf16x8*>(
            &Cout[(size_t)(m0 + row) * ldc + n0 + cb * 8]) = v;
    }
}

// ---------------- pipelined bf16 NT GEMM (GEMM2/3) ----------------
// BM=128, BN in {128,64}. Ring-3, counted vmcnt, XOR swizzle, N-fastest XCD swizzle.
template<int BN, int NT, int OUTBF, int NTB>
__global__ __launch_bounds__(256)
void gemm_bf16_pipe(const ushort* __restrict__ A, int lda,
                    const ushort* __restrict__ B, int ldb,
                    void* __restrict__ Cout, int ldc) {
    constexpr int NI  = BN / 32;
    constexpr int BNP = BN + 8;
    __shared__ __align__(16) ushort As[3][128 * 32];
    __shared__ __align__(16) ushort Bs[3][BN * 32];

    const int nwg = gridDim.x;
    const int wg  = blockIdx.x;
    const int swz = (wg & 7) * (nwg >> 3) + (wg >> 3);
    const int m0 = (swz / NTB) * 128;
    const int n0 = (swz % NTB) * BN;

    const int tid  = threadIdx.x;
    const int wave = tid >> 6;
    const int lane = tid & 63;
    const int wm = (wave & 1) * 64;
    const int wn = (wave >> 1) * (BN / 2);
    const int r16 = lane & 15;
    const int kg  = lane >> 4;
    const int pkg = kg ^ ((r16 >> 1) & 3);

    f32x4 acc[4][NI];
    #pragma unroll
    for (int i = 0; i < 4; ++i)
        #pragma unroll
        for (int j = 0; j < NI; ++j) acc[i][j] = (f32x4){0.f, 0.f, 0.f, 0.f};

    const int srow = lane >> 2;
    const int scol = ((lane & 3) ^ ((lane >> 3) & 3)) * 8;
    const int ca0 = wave * 2, ca1 = wave * 2 + 1;
    const ushort* gA0 = A + (size_t)(m0 + ca0 * 16 + srow) * lda + scol;
    const ushort* gA1 = A + (size_t)(m0 + ca1 * 16 + srow) * lda + scol;
    const ushort* gB0;
    const ushort* gB1 = nullptr;
    int cb0, cb1 = 0;
    if constexpr (BN == 128) {
        cb0 = wave * 2; cb1 = wave * 2 + 1;
        gB0 = B + (size_t)(n0 + cb0 * 16 + srow) * ldb + scol;
        gB1 = B + (size_t)(n0 + cb1 * 16 + srow) * ldb + scol;
    } else {
        cb0 = wave;
        gB0 = B + (size_t)(n0 + cb0 * 16 + srow) * ldb + scol;
    }

#define STAGE_STEP(T, BUF)                                          \
    {                                                               \
        const int _k = (T) * 32;                                    \
        gload16(gA0 + _k, &As[BUF][ca0 * 512]);                     \
        gload16(gA1 + _k, &As[BUF][ca1 * 512]);                     \
        gload16(gB0 + _k, &Bs[BUF][cb0 * 512]);                     \
        if constexpr (BN == 128) gload16(gB1 + _k, &Bs[BUF][cb1 * 512]); \
    }

    STAGE_STEP(0, 0)
    STAGE_STEP(1, 1)

    int rb = 0;
    for (int t = 0; t < NT; ++t) {
        __builtin_amdgcn_sched_barrier(0);
        if (t + 1 < NT) {
            if constexpr (BN == 128) asm volatile("s_waitcnt vmcnt(4)" ::: "memory");
            else                     asm volatile("s_waitcnt vmcnt(3)" ::: "memory");
        } else {
            asm volatile("s_waitcnt vmcnt(0)" ::: "memory");
        }
        __builtin_amdgcn_s_barrier();
        __builtin_amdgcn_sched_barrier(0);

        if (t + 2 < NT) {
            int sb = rb + 2; if (sb >= 3) sb -= 3;
            STAGE_STEP(t + 2, sb)
        }

        const ushort* ab = &As[rb][0];
        const ushort* bb = &Bs[rb][0];
        bf16x8 a[4], b[NI];
        #pragma unroll
        for (int mi = 0; mi < 4; ++mi)
            a[mi] = *reinterpret_cast<const bf16x8*>(&ab[(wm + mi * 16 + r16) * 32 + pkg * 8]);
        #pragma unroll
        for (int ni = 0; ni < NI; ++ni)
            b[ni] = *reinterpret_cast<const bf16x8*>(&bb[(wn + ni * 16 + r16) * 32 + pkg * 8]);

        __builtin_amdgcn_s_setprio(1);
        #pragma unroll
        for (int mi = 0; mi < 4; ++mi)
            #pragma unroll
            for (int ni = 0; ni < NI; ++ni)
                acc[mi][ni] = __builtin_amdgcn_mfma_f32_16x16x32_bf16(a[mi], b[ni], acc[mi][ni], 0, 0, 0);
        __builtin_amdgcn_s_setprio(0);

        rb = (rb == 2) ? 0 : rb + 1;
    }
#undef STAGE_STEP

    if constexpr (OUTBF) {
        ushort* EP = &As[0][0];
        ushort* outp = (ushort*)Cout;
        __syncthreads();
        #pragma unroll
        for (int half = 0; half < 2; ++half) {
            if ((wave & 1) == half) {
                #pragma unroll
                for (int mi = 0; mi < 4; ++mi)
                    #pragma unroll
                    for (int ni = 0; ni < NI; ++ni)
                        #pragma unroll
                        for (int r = 0; r < 4; ++r)
                            EP[(mi * 16 + kg * 4 + r) * BNP + wn + ni * 16 + r16] =
                                f2bf(acc[mi][ni][r]);
            }
            __syncthreads();
            #pragma unroll
            for (int i = 0; i < BN / 32; ++i) {
                int idx = tid + 256 * i;
                int row = idx / (BN / 8);
                int cb  = idx % (BN / 8);
                bf16x8 v = *reinterpret_cast<const bf16x8*>(&EP[row * BNP + cb * 8]);
                *reinterpret_cast<bf16x8*>(
                    &outp[(size_t)(m0 + half * 64 + row) * ldc + n0 + cb * 8]) = v;
            }
            __syncthreads();
        }
    } else {
        float* outp = (float*)Cout;
        #pragma unroll
        for (int mi = 0; mi < 4; ++mi)
            #pragma unroll
            for (int ni = 0; ni < NI; ++ni)
                #pragma unroll
                for (int r = 0; r < 4; ++r) {
                    int row = m0 + wm + mi * 16 + kg * 4 + r;
                    int col = n0 + wn + ni * 16 + r16;
                    outp[(size_t)row * ldc + col] = acc[mi][ni][r];
                }
    }
}

// ---------------- conv(width4, SAME) + SiLU ; softplus(dt)*A ; vectorized bf16 ----------------
__global__ __launch_bounds__(256)
void conv_silu_kernel(const ushort* __restrict__ zxb,
                      const float* __restrict__ conv_w,
                      const float* __restrict__ conv_b,
                      const float* __restrict__ dt_bias,
                      const float* __restrict__ A_log,
                      ushort* __restrict__ xbcs,
                      float* __restrict__ dA) {
    const int l = blockIdx.x;
    const ushort* base = zxb + (size_t)l * PROJ_LD + D_INNER;
    const short8 zero8 = (short8){0,0,0,0,0,0,0,0};
    for (int g = threadIdx.x; g < CONV_DIM / 8; g += 256) {
        const int c = g * 8;
        short8 xm = (l >= 1)
            ? *reinterpret_cast<const short8*>(base + c - PROJ_LD) : zero8;
        short8 x0 = *reinterpret_cast<const short8*>(base + c);
        short8 xp = (l + 1 < SEQLEN)
            ? *reinterpret_cast<const short8*>(base + c + PROJ_LD) : zero8;
        short8 xq = (l + 2 < SEQLEN)
            ? *reinterpret_cast<const short8*>(base + c + 2 * PROJ_LD) : zero8;
        float4 bia0 = *reinterpret_cast<const float4*>(&conv_b[c]);
        float4 bia1 = *reinterpret_cast<const float4*>(&conv_b[c + 4]);
        short8 o;
        #pragma unroll
        for (int j = 0; j < 8; ++j) {
            float4 w = *reinterpret_cast<const float4*>(&conv_w[(c + j) * 4]);
            float acc = (j < 4 ? (&bia0.x)[j] : (&bia1.x)[j - 4]);
            acc += w.x * bf2f((ushort)xm[j]);
            acc += w.y * bf2f((ushort)x0[j]);
            acc += w.z * bf2f((ushort)xp[j]);
            acc += w.w * bf2f((ushort)xq[j]);
            float s = acc / (1.0f + expf(-acc));   // silu
            o[j] = f2bf(s);
        }
        *reinterpret_cast<short8*>(&xbcs[(size_t)l * CONV_DIM + c]) = o;
    }
    if (threadIdx.x < N_HEADS) {
        int h = threadIdx.x;
        float v = bf2f(zxb[(size_t)l * PROJ_LD + (D_IN_PROJ - N_HEADS) + h]) + dt_bias[h];
        float sp = (v > 20.0f) ? v : log1pf(expf(v));
        dA[l * N_HEADS + h] = sp * (-expf(A_log[h]));
    }
}

// ---------------- KV partials ----------------
__global__ __launch_bounds__(256)
void kv_kernel(const ushort* __restrict__ xbcs,
               const float* __restrict__ dA,
               float* __restrict__ KVp) {
    __shared__ float Vs[16][132];
    __shared__ float Bsm[16][132];
    const int hp0 = blockIdx.x * 128;
    const int lc0 = blockIdx.y * (SEQLEN / KV_SPLIT);
    const int tid = threadIdx.x;
    const int ty = tid >> 4, tx = tid & 15;
    float acc[8][8];
    #pragma unroll
    for (int i = 0; i < 8; ++i)
        #pragma unroll
        for (int j = 0; j < 8; ++j) acc[i][j] = 0.0f;

    for (int ls = 0; ls < SEQLEN / KV_SPLIT; ls += 16) {
        {
            int lrow = tid >> 4;
            int p8   = (tid & 15) * 8;
            int l = lc0 + ls + lrow;
            short8 v = *reinterpret_cast<const short8*>(
                &xbcs[(size_t)l * CONV_DIM + hp0 + p8]);
            float a = dA[l * N_HEADS + ((hp0 + p8) >> 6)];
            #pragma unroll
            for (int j = 0; j < 8; ++j) Vs[lrow][p8 + j] = bf2f((ushort)v[j]) * a;
            short8 b = *reinterpret_cast<const short8*>(
                &xbcs[(size_t)l * CONV_DIM + D_INNER + p8]);
            #pragma unroll
            for (int j = 0; j < 8; ++j) Bsm[lrow][p8 + j] = bf2f((ushort)b[j]);
        }
        __syncthreads();
        #pragma unroll
        for (int k = 0; k < 16; ++k) {
            float a[8], b[8];
            *reinterpret_cast<float4*>(&a[0]) = *reinterpret_cast<const float4*>(&Vs[k][ty * 8]);
            *reinterpret_cast<float4*>(&a[4]) = *reinterpret_cast<const float4*>(&Vs[k][ty * 8 + 4]);
            *reinterpret_cast<float4*>(&b[0]) = *reinterpret_cast<const float4*>(&Bsm[k][tx * 8]);
            *reinterpret_cast<float4*>(&b[4]) = *reinterpret_cast<const float4*>(&Bsm[k][tx * 8 + 4]);
            #pragma unroll
            for (int i = 0; i < 8; ++i)
                #pragma unroll
                for (int j = 0; j < 8; ++j)
                    acc[i][j] = fmaf(a[i], b[j], acc[i][j]);
        }
        __syncthreads();
    }
    float* dst = KVp + (size_t)blockIdx.y * (D_INNER * D_STATE);
    #pragma unroll
    for (int i = 0; i < 8; ++i) {
        int hp = hp0 + ty * 8 + i;
        #pragma unroll
        for (int j = 0; j < 8; j += 4) {
            float4 v = make_float4(acc[i][j], acc[i][j+1], acc[i][j+2], acc[i][j+3]);
            *reinterpret_cast<float4*>(&dst[(size_t)hp * D_STATE + tx * 8 + j]) = v;
        }
    }
}

// ---------------- reduce KV_SPLIT partial slices -> bf16 KVT ----------------
__global__ __launch_bounds__(256)
void kv_reduce(const float* __restrict__ KVp, ushort* __restrict__ KVTb) {
    int i = blockIdx.x * 256 + threadIdx.x;
    float4 s = make_float4(0.f, 0.f, 0.f, 0.f);
    #pragma unroll
    for (int c = 0; c < KV_SPLIT; ++c) {
        float4 v = reinterpret_cast<const float4*>(KVp + (size_t)c * (D_INNER * D_STATE))[i];
        s.x += v.x; s.y += v.y; s.z += v.z; s.w += v.w;
    }
    ushort4 o;
    o.x = f2bf(s.x); o.y = f2bf(s.y); o.z = f2bf(s.z); o.w = f2bf(s.w);
    *reinterpret_cast<ushort4*>(&KVTb[i * 4]) = o;
}

// ---------------- y = LN(y1 + D*x_in) * silu(z) -> bf16 ----------------
__global__ __launch_bounds__(256)
void ln_gate_kernel(const ushort* __restrict__ y1b,
                    const ushort* __restrict__ xbcs,
                    const ushort* __restrict__ zxb,
                    const float* __restrict__ Dp,
                    const float* __restrict__ ln_w,
                    const float* __restrict__ ln_b,
                    ushort* __restrict__ yb) {
    const int l = blockIdx.x;
    const int tid = threadIdx.x;
    const int c = tid * 8;
    float y[8], z[8];
    float sum = 0.f, sumsq = 0.f;
    {
        short8 v  = *reinterpret_cast<const short8*>(&y1b[(size_t)l * D_INNER + c]);
        short8 xi = *reinterpret_cast<const short8*>(&xbcs[(size_t)l * CONV_DIM + c]);
        short8 zz = *reinterpret_cast<const short8*>(&zxb[(size_t)l * PROJ_LD + c]);
        float d = Dp[c >> 6];
        #pragma unroll
        for (int j = 0; j < 8; ++j) {
            float yv = bf2f((ushort)v[j]) + bf2f((ushort)xi[j]) * d;
            y[j] = yv;
            z[j] = bf2f((ushort)zz[j]);
            sum += yv;
            sumsq += yv * yv;
        }
    }
    #pragma unroll
    for (int off = 32; off > 0; off >>= 1) {
        sum   += __shfl_down(sum, off);
        sumsq += __shfl_down(sumsq, off);
    }
    __shared__ float red[8];
    int wid = tid >> 6;
    if ((tid & 63) == 0) { red[wid] = sum; red[4 + wid] = sumsq; }
    __syncthreads();
    sum   = red[0] + red[1] + red[2] + red[3];
    sumsq = red[4] + red[5] + red[6] + red[7];
    float mu  = sum * (1.0f / D_INNER);
    float var = sumsq * (1.0f / D_INNER) - mu * mu;
    float rs  = rsqrtf(var + LN_EPS);
    short8 o;
    #pragma unroll
    for (int j = 0; j < 8; ++j) {
        float yn = (y[j] - mu) * rs * ln_w[c + j] + ln_b[c + j];
        float g  = z[j] / (1.0f + expf(-z[j]));
        o[j] = f2bf(yn * g);
    }
    *reinterpret_cast<short8*>(&yb[(size_t)l * D_INNER + c]) = o;
}

extern "C" void kernel_launch(void* const* d_in, const int* in_sizes, int n_in,
                              void* d_out, int out_size, void* d_ws, size_t ws_size,
                              hipStream_t stream) {
    const float* x       = (const float*)d_in[0];
    const float* W_in    = (const float*)d_in[1];
    const float* conv_w  = (const float*)d_in[2];
    const float* conv_b  = (const float*)d_in[3];
    const float* dt_bias = (const float*)d_in[4];
    const float* A_log   = (const float*)d_in[5];
    const float* Dp      = (const float*)d_in[6];
    const float* ln_w    = (const float*)d_in[7];
    const float* ln_b    = (const float*)d_in[8];
    const float* W_out   = (const float*)d_in[9];
    float* out = (float*)d_out;

    // workspace layout (bytes), all 256-aligned
    char* ws = (char*)d_ws;
    ushort* zxb   = (ushort*)ws;                       // 4096*4480*2 = 36,700,160
    ushort* xbcs  = (ushort*)(ws +  36700160);         // 4096*2304*2 = 18,874,368
    ushort* y1b   = (ushort*)(ws +  55574528);         // 4096*2048*2 = 16,777,216
    ushort* yb    = (ushort*)(ws +  72351744);         // 4096*2048*2 = 16,777,216
    float*  KVp   = (float*)(ws +  89128960);          // 16*2048*128*4 = 16,777,216
    float*  dA    = (float*)(ws + 105906176);          // 4096*32*4   =    524,288
    ushort* KVTb  = (ushort*)(ws + 106430464);         // 2048*128*2  =    524,288
    ushort* Woutb = (ushort*)(ws + 106954752);         // 1024*2048*2 =  4,194,304
    ushort* xb    = (ushort*)(ws + 111149056);         // 4096*1024*2 =  8,388,608
    ushort* Winb  = (ushort*)(ws + 119537664);         // 4480*1024*2 =  9,175,040

    // fused converts for GEMM1 + GEMM3 weights
    cvt_all<<<(CVT_TOTAL + 255) / 256, 256, 0, stream>>>(x, W_in, W_out, xb, Winb, Woutb);

    // 1) zxb = bf16( x @ W_in^T )  (M=4096, N=4480(pad), K=1024=16x64) -> 560 blocks
    gemm_bf16_big<16, 35><<<16 * (PROJ_LD / 128), 512, 0, stream>>>(
        xb, DIM_IN, Winb, DIM_IN, zxb, PROJ_LD);

    // 2) conv + silu -> bf16 xbcs ; softplus(dt)*A -> dA
    conv_silu_kernel<<<SEQLEN, 256, 0, stream>>>(zxb, conv_w, conv_b, dt_bias, A_log,
                                                 xbcs, dA);

    // 3) KV partials (no atomics) then reduce -> bf16 KVT
    kv_kernel<<<dim3(16, KV_SPLIT), 256, 0, stream>>>(xbcs, dA, KVp);
    kv_reduce<<<(D_INNER * D_STATE / 4) / 256, 256, 0, stream>>>(KVp, KVTb);

    // 4) y1b = bf16( Cmat @ KVT^T )  (M=4096, N=2048, K=128); A = C-slice of xbcs
    gemm_bf16_pipe<128, 4, 1, 16><<<(D_INNER / 128) * 32, 256, 0, stream>>>(
        xbcs + (D_INNER + D_STATE), CONV_DIM, KVTb, D_STATE, y1b, D_INNER);

    // 5) y = LN(y1 + D*x_in) * silu(z) -> bf16 yb
    ln_gate_kernel<<<SEQLEN, 256, 0, stream>>>(y1b, xbcs, zxb, Dp, ln_w, ln_b, yb);

    // 6) out = y @ W_out^T  (M=4096, N=1024, K=2048) -> 512 blocks (BN=64), fp32 out
    gemm_bf16_pipe<64, 64, 0, 16><<<(DIM_IN / 64) * 32, 256, 0, stream>>>(
        yb, D_INNER, Woutb, D_INNER, out, DIM_IN);
}

// Round 13
// 188.962 us; speedup vs baseline: 1.1388x; 1.1388x over previous
//
#include <hip/hip_runtime.h>
#include <math.h>

#define SEQLEN    4096
#define DIM_IN    1024
#define D_INNER   2048
#define N_HEADS   32
#define D_STATE   128
#define CONV_DIM  2304      // D_INNER + 2*D_STATE
#define D_IN_PROJ 4384      // 2*D_INNER + 2*D_STATE + N_HEADS
#define PROJ_LD   4480      // padded to 35*128 so GEMM1 N-tiles need no guard
#define LN_EPS    1e-5f
#define KV_SPLIT  32        // L-chunks (128 l each) for the KV partial reduction

typedef __attribute__((ext_vector_type(8))) short bf16x8;
typedef __attribute__((ext_vector_type(4))) float f32x4;
typedef __attribute__((ext_vector_type(8))) short short8;

__device__ __forceinline__ ushort f2bf(float f) {
    union { float f; unsigned u; } v; v.f = f;
    unsigned u = v.u + 0x7FFFu + ((v.u >> 16) & 1u);   // RNE
    return (ushort)(u >> 16);
}
__device__ __forceinline__ float bf2f(ushort h) {
    union { unsigned u; float f; } v; v.u = ((unsigned)h) << 16;
    return v.f;
}

__device__ __forceinline__ void gload16(const void* g, void* l) {
    __builtin_amdgcn_global_load_lds(
        (const __attribute__((address_space(1))) void*)g,
        (__attribute__((address_space(3))) void*)l, 16, 0, 0);
}

// ---------------- fused fp32 -> bf16 converts (x, W_in padded, W_out) ----------------
#define XB_GROUPS   (SEQLEN * DIM_IN / 8)              // 65536
#define WIN_GROUPS  (PROJ_LD * DIM_IN / 8)             // 573440
#define WOUT_GROUPS (DIM_IN * D_INNER / 8)             // 262144
__global__ __launch_bounds__(256)
void cvt_all(const float* __restrict__ x, const float* __restrict__ W_in,
             const float* __restrict__ W_out,
             ushort* __restrict__ xb, ushort* __restrict__ Winb,
             ushort* __restrict__ Woutb) {
    int i = blockIdx.x * 256 + threadIdx.x;
    const float* src;
    ushort* dst;
    int gi;
    if (i < XB_GROUPS) {
        src = x; dst = xb; gi = i;
    } else if (i < XB_GROUPS + WIN_GROUPS) {
        gi = i - XB_GROUPS;
        int row = (gi * 8) >> 10;
        if (row >= D_IN_PROJ) {   // zero pad rows
            *reinterpret_cast<short8*>(&Winb[(size_t)gi * 8]) = (short8){0,0,0,0,0,0,0,0};
            return;
        }
        src = W_in; dst = Winb;
    } else if (i < XB_GROUPS + WIN_GROUPS + WOUT_GROUPS) {
        gi = i - (XB_GROUPS + WIN_GROUPS);
        src = W_out; dst = Woutb;
    } else return;
    float4 v0 = reinterpret_cast<const float4*>(src)[gi * 2];
    float4 v1 = reinterpret_cast<const float4*>(src)[gi * 2 + 1];
    short8 r;
    r[0] = f2bf(v0.x); r[1] = f2bf(v0.y); r[2] = f2bf(v0.z); r[3] = f2bf(v0.w);
    r[4] = f2bf(v1.x); r[5] = f2bf(v1.y); r[6] = f2bf(v1.z); r[7] = f2bf(v1.w);
    *reinterpret_cast<short8*>(&dst[(size_t)gi * 8]) = r;
}
#define CVT_TOTAL (XB_GROUPS + WIN_GROUPS + WOUT_GROUPS)

// ================= big-tile pipelined bf16 NT GEMM (GEMM1), 8 waves =================
// BM=256, BN=128, BK=32, 512 threads. Per-wave 64x64 output (4x4 frags, 8 ds_reads,
// 16 MFMA/step). Ring-3 LDS, counted vmcnt(3), XOR bank swizzle, N-fastest XCD
// swizzle. 16 waves/CU (2 blocks) for cross-wave overlap of the per-step barriers.
template<int NT, int NTB>
__global__ __launch_bounds__(512, 4)
void gemm_bf16_big(const ushort* __restrict__ A, int lda,
                   const ushort* __restrict__ B, int ldb,
                   ushort* __restrict__ Cout, int ldc) {
    __shared__ __align__(16) ushort S[3][12288];   // 72 KB

    const int nwg = gridDim.x;
    const int wg  = blockIdx.x;
    const int swz = (wg & 7) * (nwg >> 3) + (wg >> 3);   // bijective, nwg%8==0
    const int m0 = (swz / NTB) * 256;     // N-fastest: A-tile stays L2-resident
    const int n0 = (swz % NTB) * 128;

    const int tid  = threadIdx.x;
    const int wave = tid >> 6;           // 0..7
    const int lane = tid & 63;
    const int wr = wave >> 1;            // 0..3: rows wr*64
    const int wc = wave & 1;             // 0..1: cols wc*64
    const int r16 = lane & 15;
    const int kg  = lane >> 4;
    const int pkg = kg ^ ((r16 >> 1) & 3);   // T2 swizzled k-slot for ds_read

    f32x4 acc[4][4];
    #pragma unroll
    for (int i = 0; i < 4; ++i)
        #pragma unroll
        for (int j = 0; j < 4; ++j) acc[i][j] = (f32x4){0.f, 0.f, 0.f, 0.f};

    // staging: 24 chunks of 16 rows x 32 k (1 KB each); wave w stages chunks 3w..3w+2.
    const int srow = lane >> 2;
    const int scol = ((lane & 3) ^ ((lane >> 3) & 3)) * 8;   // inverse-swizzled src slot
    const ushort* gsrc[3];
    #pragma unroll
    for (int i = 0; i < 3; ++i) {
        int c = wave * 3 + i;
        gsrc[i] = (c < 16)
            ? A + (size_t)(m0 + c * 16 + srow) * lda + scol
            : B + (size_t)(n0 + (c - 16) * 16 + srow) * ldb + scol;
    }

#define STAGE_BIG(T, BUF)                                            \
    {                                                                \
        const int _k = (T) * 32;                                     \
        _Pragma("unroll")                                            \
        for (int i = 0; i < 3; ++i)                                  \
            gload16(gsrc[i] + _k, &S[BUF][(wave * 3 + i) * 512]);    \
    }

    STAGE_BIG(0, 0)
    STAGE_BIG(1, 1)

    int rb = 0;
    for (int t = 0; t < NT; ++t) {
        __builtin_amdgcn_sched_barrier(0);
        if (t + 1 < NT) {   // steady: 6 outstanding; drain step t's 3
            asm volatile("s_waitcnt vmcnt(3)" ::: "memory");
        } else {
            asm volatile("s_waitcnt vmcnt(0)" ::: "memory");
        }
        __builtin_amdgcn_s_barrier();
        __builtin_amdgcn_sched_barrier(0);

        if (t + 2 < NT) {
            int sb = rb + 2; if (sb >= 3) sb -= 3;
            STAGE_BIG(t + 2, sb)
        }

        const ushort* sp = &S[rb][0];
        bf16x8 a4[4], b4[4];
        #pragma unroll
        for (int ni = 0; ni < 4; ++ni)
            b4[ni] = *reinterpret_cast<const bf16x8*>(
                &sp[8192 + (wc * 64 + ni * 16 + r16) * 32 + pkg * 8]);
        #pragma unroll
        for (int mi = 0; mi < 4; ++mi)
            a4[mi] = *reinterpret_cast<const bf16x8*>(
                &sp[(wr * 64 + mi * 16 + r16) * 32 + pkg * 8]);
        __builtin_amdgcn_s_setprio(1);
        #pragma unroll
        for (int mi = 0; mi < 4; ++mi)
            #pragma unroll
            for (int ni = 0; ni < 4; ++ni)
                acc[mi][ni] = __builtin_amdgcn_mfma_f32_16x16x32_bf16(
                    a4[mi], b4[ni], acc[mi][ni], 0, 0, 0);
        __builtin_amdgcn_s_setprio(0);

        rb = (rb == 2) ? 0 : rb + 1;
    }
#undef STAGE_BIG

    // epilogue: acc -> LDS bf16 (256 x 136 padded, 69.6 KB <= 72 KB ring) ->
    // coalesced 16B stores by all 512 threads
    ushort* EP = &S[0][0];
    __syncthreads();
    #pragma unroll
    for (int mi = 0; mi < 4; ++mi)
        #pragma unroll
        for (int ni = 0; ni < 4; ++ni)
            #pragma unroll
            for (int r = 0; r < 4; ++r)
                EP[(wr * 64 + mi * 16 + kg * 4 + r) * 136 + wc * 64 + ni * 16 + r16] =
                    f2bf(acc[mi][ni][r]);
    __syncthreads();
    #pragma unroll
    for (int i = 0; i < 8; ++i) {
        int idx = tid + 512 * i;           // 4096 chunks of 16B over 256x128
        int row = idx >> 4;
        int cb  = idx & 15;
        bf16x8 v = *reinterpret_cast<const bf16x8*>(&EP[row * 136 + cb * 8]);
        *reinterpret_cast<bf16x8*>(
            &Cout[(size_t)(m0 + row) * ldc + n0 + cb * 8]) = v;
    }
}

// ---------------- pipelined bf16 NT GEMM (GEMM2/3) ----------------
// BM=128, BN in {128,64}. Ring-3, counted vmcnt, XOR swizzle, N-fastest XCD swizzle.
template<int BN, int NT, int OUTBF, int NTB>
__global__ __launch_bounds__(256)
void gemm_bf16_pipe(const ushort* __restrict__ A, int lda,
                    const ushort* __restrict__ B, int ldb,
                    void* __restrict__ Cout, int ldc) {
    constexpr int NI  = BN / 32;
    constexpr int BNP = BN + 8;
    __shared__ __align__(16) ushort As[3][128 * 32];
    __shared__ __align__(16) ushort Bs[3][BN * 32];

    const int nwg = gridDim.x;
    const int wg  = blockIdx.x;
    const int swz = (wg & 7) * (nwg >> 3) + (wg >> 3);
    const int m0 = (swz / NTB) * 128;
    const int n0 = (swz % NTB) * BN;

    const int tid  = threadIdx.x;
    const int wave = tid >> 6;
    const int lane = tid & 63;
    const int wm = (wave & 1) * 64;
    const int wn = (wave >> 1) * (BN / 2);
    const int r16 = lane & 15;
    const int kg  = lane >> 4;
    const int pkg = kg ^ ((r16 >> 1) & 3);

    f32x4 acc[4][NI];
    #pragma unroll
    for (int i = 0; i < 4; ++i)
        #pragma unroll
        for (int j = 0; j < NI; ++j) acc[i][j] = (f32x4){0.f, 0.f, 0.f, 0.f};

    const int srow = lane >> 2;
    const int scol = ((lane & 3) ^ ((lane >> 3) & 3)) * 8;
    const int ca0 = wave * 2, ca1 = wave * 2 + 1;
    const ushort* gA0 = A + (size_t)(m0 + ca0 * 16 + srow) * lda + scol;
    const ushort* gA1 = A + (size_t)(m0 + ca1 * 16 + srow) * lda + scol;
    const ushort* gB0;
    const ushort* gB1 = nullptr;
    int cb0, cb1 = 0;
    if constexpr (BN == 128) {
        cb0 = wave * 2; cb1 = wave * 2 + 1;
        gB0 = B + (size_t)(n0 + cb0 * 16 + srow) * ldb + scol;
        gB1 = B + (size_t)(n0 + cb1 * 16 + srow) * ldb + scol;
    } else {
        cb0 = wave;
        gB0 = B + (size_t)(n0 + cb0 * 16 + srow) * ldb + scol;
    }

#define STAGE_STEP(T, BUF)                                          \
    {                                                               \
        const int _k = (T) * 32;                                    \
        gload16(gA0 + _k, &As[BUF][ca0 * 512]);                     \
        gload16(gA1 + _k, &As[BUF][ca1 * 512]);                     \
        gload16(gB0 + _k, &Bs[BUF][cb0 * 512]);                     \
        if constexpr (BN == 128) gload16(gB1 + _k, &Bs[BUF][cb1 * 512]); \
    }

    STAGE_STEP(0, 0)
    STAGE_STEP(1, 1)

    int rb = 0;
    for (int t = 0; t < NT; ++t) {
        __builtin_amdgcn_sched_barrier(0);
        if (t + 1 < NT) {
            if constexpr (BN == 128) asm volatile("s_waitcnt vmcnt(4)" ::: "memory");
            else                     asm volatile("s_waitcnt vmcnt(3)" ::: "memory");
        } else {
            asm volatile("s_waitcnt vmcnt(0)" ::: "memory");
        }
        __builtin_amdgcn_s_barrier();
        __builtin_amdgcn_sched_barrier(0);

        if (t + 2 < NT) {
            int sb = rb + 2; if (sb >= 3) sb -= 3;
            STAGE_STEP(t + 2, sb)
        }

        const ushort* ab = &As[rb][0];
        const ushort* bb = &Bs[rb][0];
        bf16x8 a[4], b[NI];
        #pragma unroll
        for (int mi = 0; mi < 4; ++mi)
            a[mi] = *reinterpret_cast<const bf16x8*>(&ab[(wm + mi * 16 + r16) * 32 + pkg * 8]);
        #pragma unroll
        for (int ni = 0; ni < NI; ++ni)
            b[ni] = *reinterpret_cast<const bf16x8*>(&bb[(wn + ni * 16 + r16) * 32 + pkg * 8]);

        __builtin_amdgcn_s_setprio(1);
        #pragma unroll
        for (int mi = 0; mi < 4; ++mi)
            #pragma unroll
            for (int ni = 0; ni < NI; ++ni)
                acc[mi][ni] = __builtin_amdgcn_mfma_f32_16x16x32_bf16(a[mi], b[ni], acc[mi][ni], 0, 0, 0);
        __builtin_amdgcn_s_setprio(0);

        rb = (rb == 2) ? 0 : rb + 1;
    }
#undef STAGE_STEP

    if constexpr (OUTBF) {
        ushort* EP = &As[0][0];
        ushort* outp = (ushort*)Cout;
        __syncthreads();
        #pragma unroll
        for (int half = 0; half < 2; ++half) {
            if ((wave & 1) == half) {
                #pragma unroll
                for (int mi = 0; mi < 4; ++mi)
                    #pragma unroll
                    for (int ni = 0; ni < NI; ++ni)
                        #pragma unroll
                        for (int r = 0; r < 4; ++r)
                            EP[(mi * 16 + kg * 4 + r) * BNP + wn + ni * 16 + r16] =
                                f2bf(acc[mi][ni][r]);
            }
            __syncthreads();
            #pragma unroll
            for (int i = 0; i < BN / 32; ++i) {
                int idx = tid + 256 * i;
                int row = idx / (BN / 8);
                int cb  = idx % (BN / 8);
                bf16x8 v = *reinterpret_cast<const bf16x8*>(&EP[row * BNP + cb * 8]);
                *reinterpret_cast<bf16x8*>(
                    &outp[(size_t)(m0 + half * 64 + row) * ldc + n0 + cb * 8]) = v;
            }
            __syncthreads();
        }
    } else {
        float* outp = (float*)Cout;
        #pragma unroll
        for (int mi = 0; mi < 4; ++mi)
            #pragma unroll
            for (int ni = 0; ni < NI; ++ni)
                #pragma unroll
                for (int r = 0; r < 4; ++r) {
                    int row = m0 + wm + mi * 16 + kg * 4 + r;
                    int col = n0 + wn + ni * 16 + r16;
                    outp[(size_t)row * ldc + col] = acc[mi][ni][r];
                }
    }
}

// ---------------- conv(width4, SAME) + SiLU ; softplus(dt)*A ; vectorized bf16 ----------------
__global__ __launch_bounds__(256)
void conv_silu_kernel(const ushort* __restrict__ zxb,
                      const float* __restrict__ conv_w,
                      const float* __restrict__ conv_b,
                      const float* __restrict__ dt_bias,
                      const float* __restrict__ A_log,
                      ushort* __restrict__ xbcs,
                      float* __restrict__ dA) {
    const int l = blockIdx.x;
    const ushort* base = zxb + (size_t)l * PROJ_LD + D_INNER;
    const short8 zero8 = (short8){0,0,0,0,0,0,0,0};
    for (int g = threadIdx.x; g < CONV_DIM / 8; g += 256) {
        const int c = g * 8;
        short8 xm = (l >= 1)
            ? *reinterpret_cast<const short8*>(base + c - PROJ_LD) : zero8;
        short8 x0 = *reinterpret_cast<const short8*>(base + c);
        short8 xp = (l + 1 < SEQLEN)
            ? *reinterpret_cast<const short8*>(base + c + PROJ_LD) : zero8;
        short8 xq = (l + 2 < SEQLEN)
            ? *reinterpret_cast<const short8*>(base + c + 2 * PROJ_LD) : zero8;
        float4 bia0 = *reinterpret_cast<const float4*>(&conv_b[c]);
        float4 bia1 = *reinterpret_cast<const float4*>(&conv_b[c + 4]);
        short8 o;
        #pragma unroll
        for (int j = 0; j < 8; ++j) {
            float4 w = *reinterpret_cast<const float4*>(&conv_w[(c + j) * 4]);
            float acc = (j < 4 ? (&bia0.x)[j] : (&bia1.x)[j - 4]);
            acc += w.x * bf2f((ushort)xm[j]);
            acc += w.y * bf2f((ushort)x0[j]);
            acc += w.z * bf2f((ushort)xp[j]);
            acc += w.w * bf2f((ushort)xq[j]);
            float s = acc / (1.0f + expf(-acc));   // silu
            o[j] = f2bf(s);
        }
        *reinterpret_cast<short8*>(&xbcs[(size_t)l * CONV_DIM + c]) = o;
    }
    if (threadIdx.x < N_HEADS) {
        int h = threadIdx.x;
        float v = bf2f(zxb[(size_t)l * PROJ_LD + (D_IN_PROJ - N_HEADS) + h]) + dt_bias[h];
        float sp = (v > 20.0f) ? v : log1pf(expf(v));
        dA[l * N_HEADS + h] = sp * (-expf(A_log[h]));
    }
}

// ---------------- KV partials ----------------
__global__ __launch_bounds__(256)
void kv_kernel(const ushort* __restrict__ xbcs,
               const float* __restrict__ dA,
               float* __restrict__ KVp) {
    __shared__ float Vs[16][132];
    __shared__ float Bsm[16][132];
    const int hp0 = blockIdx.x * 128;
    const int lc0 = blockIdx.y * (SEQLEN / KV_SPLIT);
    const int tid = threadIdx.x;
    const int ty = tid >> 4, tx = tid & 15;
    float acc[8][8];
    #pragma unroll
    for (int i = 0; i < 8; ++i)
        #pragma unroll
        for (int j = 0; j < 8; ++j) acc[i][j] = 0.0f;

    for (int ls = 0; ls < SEQLEN / KV_SPLIT; ls += 16) {
        {
            int lrow = tid >> 4;
            int p8   = (tid & 15) * 8;
            int l = lc0 + ls + lrow;
            short8 v = *reinterpret_cast<const short8*>(
                &xbcs[(size_t)l * CONV_DIM + hp0 + p8]);
            float a = dA[l * N_HEADS + ((hp0 + p8) >> 6)];
            #pragma unroll
            for (int j = 0; j < 8; ++j) Vs[lrow][p8 + j] = bf2f((ushort)v[j]) * a;
            short8 b = *reinterpret_cast<const short8*>(
                &xbcs[(size_t)l * CONV_DIM + D_INNER + p8]);
            #pragma unroll
            for (int j = 0; j < 8; ++j) Bsm[lrow][p8 + j] = bf2f((ushort)b[j]);
        }
        __syncthreads();
        #pragma unroll
        for (int k = 0; k < 16; ++k) {
            float a[8], b[8];
            *reinterpret_cast<float4*>(&a[0]) = *reinterpret_cast<const float4*>(&Vs[k][ty * 8]);
            *reinterpret_cast<float4*>(&a[4]) = *reinterpret_cast<const float4*>(&Vs[k][ty * 8 + 4]);
            *reinterpret_cast<float4*>(&b[0]) = *reinterpret_cast<const float4*>(&Bsm[k][tx * 8]);
            *reinterpret_cast<float4*>(&b[4]) = *reinterpret_cast<const float4*>(&Bsm[k][tx * 8 + 4]);
            #pragma unroll
            for (int i = 0; i < 8; ++i)
                #pragma unroll
                for (int j = 0; j < 8; ++j)
                    acc[i][j] = fmaf(a[i], b[j], acc[i][j]);
        }
        __syncthreads();
    }
    float* dst = KVp + (size_t)blockIdx.y * (D_INNER * D_STATE);
    #pragma unroll
    for (int i = 0; i < 8; ++i) {
        int hp = hp0 + ty * 8 + i;
        #pragma unroll
        for (int j = 0; j < 8; j += 4) {
            float4 v = make_float4(acc[i][j], acc[i][j+1], acc[i][j+2], acc[i][j+3]);
            *reinterpret_cast<float4*>(&dst[(size_t)hp * D_STATE + tx * 8 + j]) = v;
        }
    }
}

// ---------------- reduce KV_SPLIT partial slices -> bf16 KVT ----------------
__global__ __launch_bounds__(256)
void kv_reduce(const float* __restrict__ KVp, ushort* __restrict__ KVTb) {
    int i = blockIdx.x * 256 + threadIdx.x;
    float4 s = make_float4(0.f, 0.f, 0.f, 0.f);
    #pragma unroll
    for (int c = 0; c < KV_SPLIT; ++c) {
        float4 v = reinterpret_cast<const float4*>(KVp + (size_t)c * (D_INNER * D_STATE))[i];
        s.x += v.x; s.y += v.y; s.z += v.z; s.w += v.w;
    }
    ushort4 o;
    o.x = f2bf(s.x); o.y = f2bf(s.y); o.z = f2bf(s.z); o.w = f2bf(s.w);
    *reinterpret_cast<ushort4*>(&KVTb[i * 4]) = o;
}

// ---------------- y = LN(y1 + D*x_in) * silu(z) -> bf16 ----------------
__global__ __launch_bounds__(256)
void ln_gate_kernel(const ushort* __restrict__ y1b,
                    const ushort* __restrict__ xbcs,
                    const ushort* __restrict__ zxb,
                    const float* __restrict__ Dp,
                    const float* __restrict__ ln_w,
                    const float* __restrict__ ln_b,
                    ushort* __restrict__ yb) {
    const int l = blockIdx.x;
    const int tid = threadIdx.x;
    const int c = tid * 8;
    float y[8], z[8];
    float sum = 0.f, sumsq = 0.f;
    {
        short8 v  = *reinterpret_cast<const short8*>(&y1b[(size_t)l * D_INNER + c]);
        short8 xi = *reinterpret_cast<const short8*>(&xbcs[(size_t)l * CONV_DIM + c]);
        short8 zz = *reinterpret_cast<const short8*>(&zxb[(size_t)l * PROJ_LD + c]);
        float d = Dp[c >> 6];
        #pragma unroll
        for (int j = 0; j < 8; ++j) {
            float yv = bf2f((ushort)v[j]) + bf2f((ushort)xi[j]) * d;
            y[j] = yv;
            z[j] = bf2f((ushort)zz[j]);
            sum += yv;
            sumsq += yv * yv;
        }
    }
    #pragma unroll
    for (int off = 32; off > 0; off >>= 1) {
        sum   += __shfl_down(sum, off);
        sumsq += __shfl_down(sumsq, off);
    }
    __shared__ float red[8];
    int wid = tid >> 6;
    if ((tid & 63) == 0) { red[wid] = sum; red[4 + wid] = sumsq; }
    __syncthreads();
    sum   = red[0] + red[1] + red[2] + red[3];
    sumsq = red[4] + red[5] + red[6] + red[7];
    float mu  = sum * (1.0f / D_INNER);
    float var = sumsq * (1.0f / D_INNER) - mu * mu;
    float rs  = rsqrtf(var + LN_EPS);
    short8 o;
    #pragma unroll
    for (int j = 0; j < 8; ++j) {
        float yn = (y[j] - mu) * rs * ln_w[c + j] + ln_b[c + j];
        float g  = z[j] / (1.0f + expf(-z[j]));
        o[j] = f2bf(yn * g);
    }
    *reinterpret_cast<short8*>(&yb[(size_t)l * D_INNER + c]) = o;
}

extern "C" void kernel_launch(void* const* d_in, const int* in_sizes, int n_in,
                              void* d_out, int out_size, void* d_ws, size_t ws_size,
                              hipStream_t stream) {
    const float* x       = (const float*)d_in[0];
    const float* W_in    = (const float*)d_in[1];
    const float* conv_w  = (const float*)d_in[2];
    const float* conv_b  = (const float*)d_in[3];
    const float* dt_bias = (const float*)d_in[4];
    const float* A_log   = (const float*)d_in[5];
    const float* Dp      = (const float*)d_in[6];
    const float* ln_w    = (const float*)d_in[7];
    const float* ln_b    = (const float*)d_in[8];
    const float* W_out   = (const float*)d_in[9];
    float* out = (float*)d_out;

    // workspace layout (bytes), all 256-aligned
    char* ws = (char*)d_ws;
    ushort* zxb   = (ushort*)ws;                       // 4096*4480*2 = 36,700,160
    ushort* xbcs  = (ushort*)(ws +  36700160);         // 4096*2304*2 = 18,874,368
    ushort* y1b   = (ushort*)(ws +  55574528);         // 4096*2048*2 = 16,777,216
    ushort* yb    = (ushort*)(ws +  72351744);         // 4096*2048*2 = 16,777,216
    float*  KVp   = (float*)(ws +  89128960);          // 32*2048*128*4 = 33,554,432
    float*  dA    = (float*)(ws + 122683392);          // 4096*32*4   =    524,288
    ushort* KVTb  = (ushort*)(ws + 123207680);         // 2048*128*2  =    524,288
    ushort* Woutb = (ushort*)(ws + 123731968);         // 1024*2048*2 =  4,194,304
    ushort* xb    = (ushort*)(ws + 127926272);         // 4096*1024*2 =  8,388,608
    ushort* Winb  = (ushort*)(ws + 136314880);         // 4480*1024*2 =  9,175,040

    // fused converts for GEMM1 + GEMM3 weights
    cvt_all<<<(CVT_TOTAL + 255) / 256, 256, 0, stream>>>(x, W_in, W_out, xb, Winb, Woutb);

    // 1) zxb = bf16( x @ W_in^T )   (M=4096, N=4480(pad), K=1024) -> 560 blocks x 512thr
    gemm_bf16_big<32, 35><<<16 * (PROJ_LD / 128), 512, 0, stream>>>(
        xb, DIM_IN, Winb, DIM_IN, zxb, PROJ_LD);

    // 2) conv + silu -> bf16 xbcs ; softplus(dt)*A -> dA
    conv_silu_kernel<<<SEQLEN, 256, 0, stream>>>(zxb, conv_w, conv_b, dt_bias, A_log,
                                                 xbcs, dA);

    // 3) KV partials (no atomics) then reduce -> bf16 KVT
    kv_kernel<<<dim3(16, KV_SPLIT), 256, 0, stream>>>(xbcs, dA, KVp);
    kv_reduce<<<(D_INNER * D_STATE / 4) / 256, 256, 0, stream>>>(KVp, KVTb);

    // 4) y1b = bf16( Cmat @ KVT^T )  (M=4096, N=2048, K=128); A = C-slice of xbcs
    gemm_bf16_pipe<128, 4, 1, 16><<<(D_INNER / 128) * 32, 256, 0, stream>>>(
        xbcs + (D_INNER + D_STATE), CONV_DIM, KVTb, D_STATE, y1b, D_INNER);

    // 5) y = LN(y1 + D*x_in) * silu(z) -> bf16 yb
    ln_gate_kernel<<<SEQLEN, 256, 0, stream>>>(y1b, xbcs, zxb, Dp, ln_w, ln_b, yb);

    // 6) out = y @ W_out^T  (M=4096, N=1024, K=2048) -> 512 blocks (BN=64), fp32 out
    gemm_bf16_pipe<64, 64, 0, 16><<<(DIM_IN / 64) * 32, 256, 0, stream>>>(
        yb, D_INNER, Woutb, D_INNER, out, DIM_IN);
}